// Round 20
// baseline (750.230 us; speedup 1.0000x reference)
//
#include <hip/hip_runtime.h>
#include <math.h>

#define B_ROWS 8192
#define P_KEYS 2048
#define D_DIM  768
#define L_LEN  5
#define K_SEL  5
#define EPSV   1e-8f

#define RTILE 256
#define CTILE 64
#define KB 32
#define NCB (P_KEYS / CTILE)      // 32 column blocks
#define NCAND (NCB * K_SEL)       // 160 candidates per row
#define BSTRIDE 36                // B col stride in floats (16B-aligned, spreads banks)

// sorted ascending (v[0] best). Tie-break: lower index wins (jax top_k semantics).
__device__ inline void insert5(float (&v)[K_SEL], int (&ix)[K_SEL], float nv, int ni) {
    if (nv < v[K_SEL-1] || (nv == v[K_SEL-1] && ni < ix[K_SEL-1])) {
        v[K_SEL-1] = nv; ix[K_SEL-1] = ni;
        #pragma unroll
        for (int j = K_SEL-1; j > 0; --j) {
            bool sw = (v[j] < v[j-1]) || (v[j] == v[j-1] && ix[j] < ix[j-1]);
            if (sw) {
                float tv = v[j]; v[j] = v[j-1]; v[j-1] = tv;
                int   ti = ix[j]; ix[j] = ix[j-1]; ix[j-1] = ti;
            }
        }
    }
}

// One wave (64 lanes) per row. waves [0, P_KEYS): normalize pool_key -> kn.
// waves [P_KEYS, ...): x -> inv_x only.  [r14-verbatim]
__global__ __launch_bounds__(256)
void norm_kernel(const float* __restrict__ x, const float* __restrict__ pk,
                 float* __restrict__ kn, float* __restrict__ inv_x) {
    int wave = (blockIdx.x * blockDim.x + threadIdx.x) >> 6;
    int lane = threadIdx.x & 63;
    bool is_key = (wave < P_KEYS);
    int row = is_key ? wave : wave - P_KEYS;
    const float* src = is_key ? (pk + (size_t)row * D_DIM) : (x + (size_t)row * D_DIM);

    const float4* s4 = (const float4*)src;
    float4 v[3];
    float s = 0.f;
    #pragma unroll
    for (int i = 0; i < 3; ++i) {
        v[i] = s4[lane + 64 * i];
        s += v[i].x * v[i].x + v[i].y * v[i].y + v[i].z * v[i].z + v[i].w * v[i].w;
    }
    #pragma unroll
    for (int off = 32; off; off >>= 1) s += __shfl_xor(s, off, 64);
    float inv = 1.0f / fmaxf(sqrtf(s), EPSV);

    if (is_key) {
        float4* d4 = (float4*)(kn + (size_t)row * D_DIM);
        #pragma unroll
        for (int i = 0; i < 3; ++i) {
            float4 w = v[i];
            w.x *= inv; w.y *= inv; w.z *= inv; w.w *= inv;
            d4[lane + 64 * i] = w;
        }
    } else {
        if (lane == 0) inv_x[row] = inv;
    }
}

// Fused fp32 GEMM (dist = 1 - x_hat . k_hat) + per-row top-5 per 64-col block.
// r19 post-mortem: VALUBusy 58% with FMA demand 37% -> ~42% stall. Theory:
// s_load (SMEM) and ds_read (LDS) SHARE lgkmcnt, and SMEM returns out of
// order, so the compiler must drain lgkmcnt(0) before every consume when the
// loop mixes them -> scalar-load latency lands on the critical path 4x/slab.
// FIX: B staged into LDS too (Bs[64][36], 1 float4/thread/slab, prefetched)
// and read via WAVE-UNIFORM ds_read broadcasts (same addr across lanes =
// conflict-free). Inner loop is now pure-LDS -> in-order, fine-grained
// lgkmcnt(N) waits (m97 behavior). b values + accumulation order bitwise
// unchanged from r14/r19. grid = (32, 32), block = 512 (8 waves x 8 cols),
// 4 rows/lane.
__global__ __launch_bounds__(512)
void gemm_top5_kernel(const float* __restrict__ x, const float* __restrict__ kn,
                      const float* __restrict__ inv_x,
                      float* __restrict__ cand_val, int* __restrict__ cand_idx) {
    const int cb   = blockIdx.x;
    const int rb   = blockIdx.y;
    const int row0 = rb * RTILE;
    const int tid  = threadIdx.x;
    const int lane = tid & 63;
    const int w    = __builtin_amdgcn_readfirstlane(tid >> 6);  // wave id 0..7
    const int col0w = cb * CTILE + w * 8;                        // this wave's 8 cols

    // ~41 KB LDS, time-shared: phase 1 = As[256][32] + Bs[64][36]; phase 2 = merge
    __shared__ float smem[10496];
    float* As   = smem;                    // 8192 floats (XOR-swizzled quads)
    float* Bs   = smem + 8192;             // 2304 floats
    float* mval = smem;                    // merge phase: [256 rows][4 slots][5]
    int*   midx = (int*)smem + 256 * 4 * K_SEL;

    // A staging: 512 threads x 4 float4 = 256 rows x 32 k
    const int sr = tid >> 3;               // 0..63
    const int sq = tid & 7;                // col-quad
    const int wq = (sq ^ (sr & 7)) * 4;    // swizzled (row&7 same for all 4 rows)
    const float* ap0 = x + (size_t)(row0 + sr) * D_DIM + sq * 4;
    float iva[4];
    #pragma unroll
    for (int m = 0; m < 4; ++m) iva[m] = inv_x[row0 + sr + 64 * m];

    // B staging: thread t -> col t>>3 (0..63), k-quad t&7
    const float* bp0 = kn + (size_t)(cb * CTILE + sr) * D_DIM + sq * 4;

    const int swz = lane & 7;
    float acc[4][8] = {};

    float4 pf[4], pb;
    #pragma unroll
    for (int m = 0; m < 4; ++m)
        pf[m] = *(const float4*)(ap0 + (size_t)m * 64 * D_DIM);
    pb = *(const float4*)(bp0);

    for (int k0 = 0; k0 < D_DIM; k0 += KB) {
        __syncthreads();
        #pragma unroll
        for (int m = 0; m < 4; ++m) {
            float4 t = pf[m];
            t.x *= iva[m]; t.y *= iva[m]; t.z *= iva[m]; t.w *= iva[m];
            *(float4*)&As[(sr + 64 * m) * 32 + wq] = t;
        }
        *(float4*)&Bs[sr * BSTRIDE + sq * 4] = pb;
        __syncthreads();
        int knext = (k0 + KB < D_DIM) ? (k0 + KB) : 0;
        #pragma unroll
        for (int m = 0; m < 4; ++m)
            pf[m] = *(const float4*)(ap0 + (size_t)m * 64 * D_DIM + knext);
        pb = *(const float4*)(bp0 + knext);

        #pragma unroll
        for (int ch = 0; ch < 4; ++ch) {   // 8-k chunks
            const int q0 = ((2 * ch) ^ swz) * 4;
            const int q1 = ((2 * ch + 1) ^ swz) * 4;
            float a[4][8];
            #pragma unroll
            for (int m = 0; m < 4; ++m) {
                float4 lo = *(const float4*)&As[(lane + 64 * m) * 32 + q0];
                float4 hi = *(const float4*)&As[(lane + 64 * m) * 32 + q1];
                a[m][0] = lo.x; a[m][1] = lo.y; a[m][2] = lo.z; a[m][3] = lo.w;
                a[m][4] = hi.x; a[m][5] = hi.y; a[m][6] = hi.z; a[m][7] = hi.w;
            }
            #pragma unroll
            for (int c = 0; c < 8; ++c) {
                // wave-uniform LDS address -> broadcast ds_read (conflict-free)
                float4 bl = *(const float4*)&Bs[(w * 8 + c) * BSTRIDE + ch * 8];
                float4 bh = *(const float4*)&Bs[(w * 8 + c) * BSTRIDE + ch * 8 + 4];
                float b[8] = {bl.x, bl.y, bl.z, bl.w, bh.x, bh.y, bh.z, bh.w};
                #pragma unroll
                for (int j = 0; j < 8; ++j) {
                    #pragma unroll
                    for (int m = 0; m < 4; ++m)
                        acc[m][c] += a[m][j] * b[j];
                }
            }
        }
    }

    // epilogue: per-lane top5 per row over this wave's 8 cols
    float tv[4][K_SEL]; int ti[4][K_SEL];
    #pragma unroll
    for (int m = 0; m < 4; ++m)
        #pragma unroll
        for (int j = 0; j < K_SEL; ++j) { tv[m][j] = 3.0e38f; ti[m][j] = 0x7fffffff; }
    #pragma unroll
    for (int m = 0; m < 4; ++m)
        #pragma unroll
        for (int c = 0; c < 8; ++c)
            insert5(tv[m], ti[m], 1.0f - acc[m][c], col0w + c);

    // pairwise wave-tree merge: 4-7 -> 0-3, 2-3 -> 0-1, 1 -> 0 (slots 0..3)
    #pragma unroll
    for (int hb = 4; hb >= 1; hb >>= 1) {
        __syncthreads();
        if (w >= hb && w < 2 * hb) {
            int s = w - hb;
            #pragma unroll
            for (int m = 0; m < 4; ++m)
                #pragma unroll
                for (int j = 0; j < K_SEL; ++j) {
                    mval[((lane + 64 * m) * 4 + s) * K_SEL + j] = tv[m][j];
                    midx[((lane + 64 * m) * 4 + s) * K_SEL + j] = ti[m][j];
                }
        }
        __syncthreads();
        if (w < hb) {
            #pragma unroll
            for (int m = 0; m < 4; ++m)
                #pragma unroll
                for (int j = 0; j < K_SEL; ++j)
                    insert5(tv[m], ti[m],
                            mval[((lane + 64 * m) * 4 + w) * K_SEL + j],
                            midx[((lane + 64 * m) * 4 + w) * K_SEL + j]);
        }
    }

    if (w == 0) {
        #pragma unroll
        for (int m = 0; m < 4; ++m) {
            int grow = row0 + lane + 64 * m;
            #pragma unroll
            for (int j = 0; j < K_SEL; ++j) {
                cand_val[((size_t)grow * NCB + cb) * K_SEL + j] = tv[m][j];
                cand_idx[((size_t)grow * NCB + cb) * K_SEL + j] = ti[m][j];
            }
        }
    }
}

// FUSED merge + gather [r19-verbatim, passed]: one block per row. LDS-stage
// the 160 candidates, thread 0 runs the serial insert5 (t = 0..159) ->
// identical selection semantics; then 256 threads copy the 5 prompt slabs.
__global__ __launch_bounds__(256)
void select_gather_kernel(const float* __restrict__ cand_val,
                          const int* __restrict__ cand_idx,
                          const float* __restrict__ prompts,
                          float* __restrict__ out_dist, float* __restrict__ out_pr) {
    const int row = blockIdx.x;
    const int tid = threadIdx.x;
    __shared__ float sv[NCAND];
    __shared__ int   si[NCAND];
    __shared__ int   sfi[K_SEL];

    if (tid < NCAND) {
        sv[tid] = cand_val[(size_t)row * NCAND + tid];
        si[tid] = cand_idx[(size_t)row * NCAND + tid];
    }
    __syncthreads();

    if (tid == 0) {
        float fv[K_SEL]; int fi[K_SEL];
        #pragma unroll
        for (int j = 0; j < K_SEL; ++j) { fv[j] = 3.0e38f; fi[j] = 0x7fffffff; }
        for (int t = 0; t < NCAND; ++t) insert5(fv, fi, sv[t], si[t]);
        #pragma unroll
        for (int j = 0; j < K_SEL; ++j) {
            out_dist[(size_t)row * K_SEL + j] = fv[j];
            sfi[j] = fi[j];
        }
    }
    __syncthreads();

    // copy prompts[sfi[s]] (960 float4 each) to out_pr[row][s]
    #pragma unroll
    for (int s = 0; s < K_SEL; ++s) {
        const float4* src = (const float4*)(prompts + (size_t)sfi[s] * (L_LEN * D_DIM));
        float4* dst = (float4*)(out_pr + ((size_t)row * K_SEL + s) * (L_LEN * D_DIM));
        for (int i = tid; i < (L_LEN * D_DIM) / 4; i += 256) dst[i] = src[i];
    }
}

extern "C" void kernel_launch(void* const* d_in, const int* in_sizes, int n_in,
                              void* d_out, int out_size, void* d_ws, size_t ws_size,
                              hipStream_t stream) {
    const float* x       = (const float*)d_in[0];   // [8192, 768]
    const float* pk      = (const float*)d_in[1];   // [2048, 768]
    const float* prompts = (const float*)d_in[2];   // [2048, 5, 768]

    float* out_dist = (float*)d_out;                          // [8192, 5]
    float* out_pr   = (float*)d_out + (size_t)B_ROWS * K_SEL; // [8192, 5, 5, 768]

    char* ws = (char*)d_ws;
    float* kn       = (float*)(ws);                               // 6,291,456 B
    float* inv_x    = (float*)(ws + 6291456);                     //    32,768 B
    float* cand_val = (float*)(ws + 6324224);                     // 5,242,880 B
    int*   cand_idx = (int*)  (ws + 6324224 + 5242880);           // 5,242,880 B

    // 1) normalize keys -> kn; inverse norms for x
    norm_kernel<<<(P_KEYS + B_ROWS) / 4, 256, 0, stream>>>(x, pk, kn, inv_x);
    // 2) fused GEMM (pure-LDS inner loop: A swizzled, B broadcast) + top5
    {
        dim3 grid(NCB, B_ROWS / RTILE);
        gemm_top5_kernel<<<grid, 512, 0, stream>>>(x, kn, inv_x, cand_val, cand_idx);
    }
    // 3) fused cross-colblock top-5 merge + prompt gather
    select_gather_kernel<<<B_ROWS, 256, 0, stream>>>(cand_val, cand_idx, prompts,
                                                     out_dist, out_pr);
}

// Round 21
// 596.108 us; speedup vs baseline: 1.2585x; 1.2585x over previous
//
#include <hip/hip_runtime.h>
#include <math.h>

#define B_ROWS 8192
#define P_KEYS 2048
#define D_DIM  768
#define L_LEN  5
#define K_SEL  5
#define EPSV   1e-8f

#define RTILE 256
#define CTILE 64
#define KB 32
#define NCB (P_KEYS / CTILE)      // 32 column blocks
#define NCAND (NCB * K_SEL)       // 160 candidates per row

// sorted ascending (v[0] best). Tie-break: lower index wins (jax top_k semantics).
__device__ inline void insert5(float (&v)[K_SEL], int (&ix)[K_SEL], float nv, int ni) {
    if (nv < v[K_SEL-1] || (nv == v[K_SEL-1] && ni < ix[K_SEL-1])) {
        v[K_SEL-1] = nv; ix[K_SEL-1] = ni;
        #pragma unroll
        for (int j = K_SEL-1; j > 0; --j) {
            bool sw = (v[j] < v[j-1]) || (v[j] == v[j-1] && ix[j] < ix[j-1]);
            if (sw) {
                float tv = v[j]; v[j] = v[j-1]; v[j-1] = tv;
                int   ti = ix[j]; ix[j] = ix[j-1]; ix[j-1] = ti;
            }
        }
    }
}

// One wave (64 lanes) per row. waves [0, P_KEYS): normalize pool_key -> kn.
// waves [P_KEYS, ...): x -> inv_x only.  [r14-verbatim]
__global__ __launch_bounds__(256)
void norm_kernel(const float* __restrict__ x, const float* __restrict__ pk,
                 float* __restrict__ kn, float* __restrict__ inv_x) {
    int wave = (blockIdx.x * blockDim.x + threadIdx.x) >> 6;
    int lane = threadIdx.x & 63;
    bool is_key = (wave < P_KEYS);
    int row = is_key ? wave : wave - P_KEYS;
    const float* src = is_key ? (pk + (size_t)row * D_DIM) : (x + (size_t)row * D_DIM);

    const float4* s4 = (const float4*)src;
    float4 v[3];
    float s = 0.f;
    #pragma unroll
    for (int i = 0; i < 3; ++i) {
        v[i] = s4[lane + 64 * i];
        s += v[i].x * v[i].x + v[i].y * v[i].y + v[i].z * v[i].z + v[i].w * v[i].w;
    }
    #pragma unroll
    for (int off = 32; off; off >>= 1) s += __shfl_xor(s, off, 64);
    float inv = 1.0f / fmaxf(sqrtf(s), EPSV);

    if (is_key) {
        float4* d4 = (float4*)(kn + (size_t)row * D_DIM);
        #pragma unroll
        for (int i = 0; i < 3; ++i) {
            float4 w = v[i];
            w.x *= inv; w.y *= inv; w.z *= inv; w.w *= inv;
            d4[lane + 64 * i] = w;
        }
    } else {
        if (lane == 0) inv_x[row] = inv;
    }
}

// Fused fp32 GEMM (dist = 1 - x_hat . k_hat) + per-row top-5 per 64-col block.
// Inner loop = r14-verbatim (best measured: 438 us, VALU 58%, VGPR 56).
// r20's B-through-LDS variant regressed (VGPR 112, occ 22.6%, 652 us) — reverted.
//
// CHANGE vs r14: the epilogue merge is split into TWO row-phases so the
// merge LDS halves (mval/midx[128][4][5] = 20 KB), letting smem shrink from
// 40 KB -> 32 KB (= exactly what As needs). At 40 KB the block LDS capped
// residency (~2 blocks/CU, occupancy 42%); at 32 KB up to 4 blocks/CU of
// 512 thr fit with slack -> more waves to hide the s_load latency chains.
// Selection semantics unchanged: insert5 is a total-order (value,index)
// selector, so top-5-of-union is merge-order independent.
// grid = (NCB, B_ROWS/RTILE) = (32, 32), block = 512 (8 waves x 8 cols).
__global__ __launch_bounds__(512)
void gemm_top5_kernel(const float* __restrict__ x, const float* __restrict__ kn,
                      const float* __restrict__ inv_x,
                      float* __restrict__ cand_val, int* __restrict__ cand_idx) {
    const int cb   = blockIdx.x;
    const int rb   = blockIdx.y;
    const int row0 = rb * RTILE;
    const int tid  = threadIdx.x;
    const int lane = tid & 63;
    const int w    = __builtin_amdgcn_readfirstlane(tid >> 6);  // wave id 0..7
    const int col0w = cb * CTILE + w * 8;                        // this wave's 8 cols

    // 32 KB LDS, time-shared: phase 1 = As[256][32]; phase 2 = merge (20 KB)
    __shared__ float smem[8192];
    float* As   = smem;
    float* mval = smem;                    // [128 rows][4 slots][5]
    int*   midx = (int*)smem + 128 * 4 * K_SEL;   // after 2560 floats

    // A staging: 512 threads x 4 float4 = 256 rows x 32 k
    const int sr = tid >> 3;               // 0..63
    const int sq = tid & 7;                // col-quad
    const int wq = (sq ^ (sr & 7)) * 4;    // swizzled (row&7 same for all 4 rows)
    const float* ap0 = x + (size_t)(row0 + sr) * D_DIM + sq * 4;
    float iva[4];
    #pragma unroll
    for (int m = 0; m < 4; ++m) iva[m] = inv_x[row0 + sr + 64 * m];

    const int swz = lane & 7;
    float acc[4][8] = {};

    float4 pf[4];
    #pragma unroll
    for (int m = 0; m < 4; ++m)
        pf[m] = *(const float4*)(ap0 + (size_t)m * 64 * D_DIM);

    for (int k0 = 0; k0 < D_DIM; k0 += KB) {
        __syncthreads();
        #pragma unroll
        for (int m = 0; m < 4; ++m) {
            float4 t = pf[m];
            t.x *= iva[m]; t.y *= iva[m]; t.z *= iva[m]; t.w *= iva[m];
            *(float4*)&As[(sr + 64 * m) * 32 + wq] = t;
        }
        __syncthreads();
        int knext = (k0 + KB < D_DIM) ? (k0 + KB) : 0;
        #pragma unroll
        for (int m = 0; m < 4; ++m)
            pf[m] = *(const float4*)(ap0 + (size_t)m * 64 * D_DIM + knext);

        #pragma unroll
        for (int ch = 0; ch < 4; ++ch) {   // 8-k chunks
            const int q0 = ((2 * ch) ^ swz) * 4;
            const int q1 = ((2 * ch + 1) ^ swz) * 4;
            float a[4][8];
            #pragma unroll
            for (int m = 0; m < 4; ++m) {
                float4 lo = *(const float4*)&As[(lane + 64 * m) * 32 + q0];
                float4 hi = *(const float4*)&As[(lane + 64 * m) * 32 + q1];
                a[m][0] = lo.x; a[m][1] = lo.y; a[m][2] = lo.z; a[m][3] = lo.w;
                a[m][4] = hi.x; a[m][5] = hi.y; a[m][6] = hi.z; a[m][7] = hi.w;
            }
            #pragma unroll
            for (int c = 0; c < 8; ++c) {
                // wave-uniform address -> s_load (SGPR b-operand in v_fma)
                const float* bp = kn + (size_t)(col0w + c) * D_DIM + k0 + ch * 8;
                #pragma unroll
                for (int j = 0; j < 8; ++j) {
                    float b = bp[j];
                    #pragma unroll
                    for (int m = 0; m < 4; ++m)
                        acc[m][c] += a[m][j] * b;
                }
            }
        }
    }

    // epilogue: per-lane top5 per row over this wave's 8 cols
    float tv[4][K_SEL]; int ti[4][K_SEL];
    #pragma unroll
    for (int m = 0; m < 4; ++m)
        #pragma unroll
        for (int j = 0; j < K_SEL; ++j) { tv[m][j] = 3.0e38f; ti[m][j] = 0x7fffffff; }
    #pragma unroll
    for (int m = 0; m < 4; ++m)
        #pragma unroll
        for (int c = 0; c < 8; ++c)
            insert5(tv[m], ti[m], 1.0f - acc[m][c], col0w + c);

    // TWO-PHASE pairwise wave-tree merge (halves merge LDS; order-independent)
    #pragma unroll
    for (int ph = 0; ph < 2; ++ph) {       // ph 0: rows lane+{0,64}; ph 1: +{128,192}
        #pragma unroll
        for (int hb = 4; hb >= 1; hb >>= 1) {
            __syncthreads();
            if (w >= hb && w < 2 * hb) {
                int s = w - hb;
                #pragma unroll
                for (int mm = 0; mm < 2; ++mm) {
                    int m = ph * 2 + mm;
                    #pragma unroll
                    for (int j = 0; j < K_SEL; ++j) {
                        mval[((lane + 64 * mm) * 4 + s) * K_SEL + j] = tv[m][j];
                        midx[((lane + 64 * mm) * 4 + s) * K_SEL + j] = ti[m][j];
                    }
                }
            }
            __syncthreads();
            if (w < hb) {
                #pragma unroll
                for (int mm = 0; mm < 2; ++mm) {
                    int m = ph * 2 + mm;
                    #pragma unroll
                    for (int j = 0; j < K_SEL; ++j)
                        insert5(tv[m], ti[m],
                                mval[((lane + 64 * mm) * 4 + w) * K_SEL + j],
                                midx[((lane + 64 * mm) * 4 + w) * K_SEL + j]);
                }
            }
        }
        if (w == 0) {
            #pragma unroll
            for (int mm = 0; mm < 2; ++mm) {
                int m = ph * 2 + mm;
                int grow = row0 + lane + 64 * m;
                #pragma unroll
                for (int j = 0; j < K_SEL; ++j) {
                    cand_val[((size_t)grow * NCB + cb) * K_SEL + j] = tv[m][j];
                    cand_idx[((size_t)grow * NCB + cb) * K_SEL + j] = ti[m][j];
                }
            }
        }
    }
}

// FUSED merge + gather [r19-verbatim, passed]: one block per row. LDS-stage
// the 160 candidates, thread 0 runs the serial insert5 (t = 0..159) ->
// identical selection semantics; then 256 threads copy the 5 prompt slabs.
__global__ __launch_bounds__(256)
void select_gather_kernel(const float* __restrict__ cand_val,
                          const int* __restrict__ cand_idx,
                          const float* __restrict__ prompts,
                          float* __restrict__ out_dist, float* __restrict__ out_pr) {
    const int row = blockIdx.x;
    const int tid = threadIdx.x;
    __shared__ float sv[NCAND];
    __shared__ int   si[NCAND];
    __shared__ int   sfi[K_SEL];

    if (tid < NCAND) {
        sv[tid] = cand_val[(size_t)row * NCAND + tid];
        si[tid] = cand_idx[(size_t)row * NCAND + tid];
    }
    __syncthreads();

    if (tid == 0) {
        float fv[K_SEL]; int fi[K_SEL];
        #pragma unroll
        for (int j = 0; j < K_SEL; ++j) { fv[j] = 3.0e38f; fi[j] = 0x7fffffff; }
        for (int t = 0; t < NCAND; ++t) insert5(fv, fi, sv[t], si[t]);
        #pragma unroll
        for (int j = 0; j < K_SEL; ++j) {
            out_dist[(size_t)row * K_SEL + j] = fv[j];
            sfi[j] = fi[j];
        }
    }
    __syncthreads();

    // copy prompts[sfi[s]] (960 float4 each) to out_pr[row][s]
    #pragma unroll
    for (int s = 0; s < K_SEL; ++s) {
        const float4* src = (const float4*)(prompts + (size_t)sfi[s] * (L_LEN * D_DIM));
        float4* dst = (float4*)(out_pr + ((size_t)row * K_SEL + s) * (L_LEN * D_DIM));
        for (int i = tid; i < (L_LEN * D_DIM) / 4; i += 256) dst[i] = src[i];
    }
}

extern "C" void kernel_launch(void* const* d_in, const int* in_sizes, int n_in,
                              void* d_out, int out_size, void* d_ws, size_t ws_size,
                              hipStream_t stream) {
    const float* x       = (const float*)d_in[0];   // [8192, 768]
    const float* pk      = (const float*)d_in[1];   // [2048, 768]
    const float* prompts = (const float*)d_in[2];   // [2048, 5, 768]

    float* out_dist = (float*)d_out;                          // [8192, 5]
    float* out_pr   = (float*)d_out + (size_t)B_ROWS * K_SEL; // [8192, 5, 5, 768]

    char* ws = (char*)d_ws;
    float* kn       = (float*)(ws);                               // 6,291,456 B
    float* inv_x    = (float*)(ws + 6291456);                     //    32,768 B
    float* cand_val = (float*)(ws + 6324224);                     // 5,242,880 B
    int*   cand_idx = (int*)  (ws + 6324224 + 5242880);           // 5,242,880 B

    // 1) normalize keys -> kn; inverse norms for x
    norm_kernel<<<(P_KEYS + B_ROWS) / 4, 256, 0, stream>>>(x, pk, kn, inv_x);
    // 2) fused GEMM (s_load B, LDS A, 4 rows/lane; 32 KB LDS) + top5
    {
        dim3 grid(NCB, B_ROWS / RTILE);
        gemm_top5_kernel<<<grid, 512, 0, stream>>>(x, kn, inv_x, cand_val, cand_idx);
    }
    // 3) fused cross-colblock top-5 merge + prompt gather
    select_gather_kernel<<<B_ROWS, 256, 0, stream>>>(cand_val, cand_idx, prompts,
                                                     out_dist, out_pr);
}